// Round 1
// baseline (1013.595 us; speedup 1.0000x reference)
//
#include <hip/hip_runtime.h>
#include <cstddef>

#define N_NODES 100000
#define N_EDGES 1600000
#define D 128
#define DOUT 64

// ---------------- graph structure ----------------

__global__ __launch_bounds__(256) void deg_kernel(const int* __restrict__ dst,
                                                  int* __restrict__ deg) {
  int e = blockIdx.x * 256 + threadIdx.x;
  if (e < N_EDGES) atomicAdd(&deg[dst[e]], 1);
}

__global__ __launch_bounds__(1024) void scan_kernel(const int* __restrict__ deg,
                                                    int* __restrict__ row_ptr,
                                                    int* __restrict__ cursor,
                                                    float* __restrict__ inv_deg) {
  __shared__ int buf[1024];
  __shared__ int carry_s;
  if (threadIdx.x == 0) carry_s = 0;
  __syncthreads();
  const int n = N_NODES;
  for (int base = 0; base < n; base += 4096) {
    int i0 = base + threadIdx.x * 4;
    int v[4];
#pragma unroll
    for (int j = 0; j < 4; j++) {
      int i = i0 + j;
      v[j] = (i < n) ? deg[i] : 0;
    }
    int s = v[0] + v[1] + v[2] + v[3];
    buf[threadIdx.x] = s;
    int acc = s;
    __syncthreads();
    for (int off = 1; off < 1024; off <<= 1) {
      int t = (threadIdx.x >= off) ? buf[threadIdx.x - off] : 0;
      __syncthreads();
      acc += t;
      buf[threadIdx.x] = acc;
      __syncthreads();
    }
    int carry = carry_s;
    int run = carry + acc - s;  // exclusive prefix at i0
#pragma unroll
    for (int j = 0; j < 4; j++) {
      int i = i0 + j;
      if (i < n) {
        row_ptr[i] = run;
        cursor[i] = run;
        inv_deg[i] = 1.0f / fmaxf((float)v[j], 1.0f);
        run += v[j];
      }
    }
    __syncthreads();
    if (threadIdx.x == 1023) carry_s = carry + acc;
    __syncthreads();
  }
  if (threadIdx.x == 0) row_ptr[n] = carry_s;
}

__global__ __launch_bounds__(256) void fill_kernel(const int* __restrict__ src,
                                                   const int* __restrict__ dst,
                                                   int* __restrict__ cursor,
                                                   int* __restrict__ csr_src) {
  int e = blockIdx.x * 256 + threadIdx.x;
  if (e < N_EDGES) {
    int pos = atomicAdd(&cursor[dst[e]], 1);
    csr_src[pos] = src[e];
  }
}

// ---------------- aggregation (mean of neighbors) ----------------
// one node per 32 lanes; float4 per lane covers 128 feats; CSR gather, no atomics

__global__ __launch_bounds__(256) void agg_kernel(const float* __restrict__ h,
                                                  const int* __restrict__ row_ptr,
                                                  const int* __restrict__ csr_src,
                                                  const float* __restrict__ inv_deg,
                                                  float* __restrict__ aggout) {
  int node = blockIdx.x * 8 + (threadIdx.x >> 5);
  if (node >= N_NODES) return;
  int lane = threadIdx.x & 31;
  int p0 = row_ptr[node], p1 = row_ptr[node + 1];
  float ax = 0.f, ay = 0.f, az = 0.f, aw = 0.f;
  for (int p = p0; p < p1; ++p) {
    int s = csr_src[p];
    float4 v = *reinterpret_cast<const float4*>(h + (size_t)s * D + lane * 4);
    ax += v.x; ay += v.y; az += v.z; aw += v.w;
  }
  float sc = inv_deg[node];
  float4 o = make_float4(ax * sc, ay * sc, az * sc, aw * sc);
  *reinterpret_cast<float4*>(aggout + (size_t)node * D + lane * 4) = o;
}

// ---------------- fused GEMM: out = [relu]( A@WL (+ H@WR) + bias ) ----------------
// BR=64 rows/block, thread = 4 rows x 8 cols, k-chunked by 32, operands in LDS.

template <int NCOLS, bool HAS_R, bool RELU>
__global__ void gemm_kernel(const float* __restrict__ A, const float* __restrict__ H,
                            const float* __restrict__ WL, const float* __restrict__ WR,
                            const float* __restrict__ bias, float* __restrict__ out) {
  constexpr int BR = 64;
  constexpr int CG = NCOLS / 8;            // col groups of 8
  constexpr int NT = (BR / 4) * CG;        // threads: 256 (NCOLS=128) / 128 (NCOLS=64)
  __shared__ float a_s[BR][36];            // padded stride 36 (16B-aligned rows, bank-spread)
  __shared__ float h_s[HAS_R ? BR : 1][36];
  __shared__ float wl_s[32][NCOLS];
  __shared__ float wr_s[32][HAS_R ? NCOLS : 8];

  const int tid = threadIdx.x;
  const int cg = tid % CG;
  const int rg = tid / CG;
  const int row0 = blockIdx.x * BR;
  const int c0 = cg * 8;

  float acc[4][8];
#pragma unroll
  for (int i = 0; i < 4; i++)
#pragma unroll
    for (int j = 0; j < 8; j++) acc[i][j] = 0.f;

  for (int kc = 0; kc < D; kc += 32) {
    __syncthreads();  // protect LDS from previous chunk's readers
    // stage row tiles: BR x 32 floats = BR*8 float4
    for (int idx = tid; idx < BR * 8; idx += NT) {
      int r = idx >> 3, q = idx & 7;
      int grow = row0 + r;
      float4 va = make_float4(0.f, 0.f, 0.f, 0.f);
      float4 vh = make_float4(0.f, 0.f, 0.f, 0.f);
      if (grow < N_NODES) {
        va = *reinterpret_cast<const float4*>(A + (size_t)grow * D + kc + q * 4);
        if constexpr (HAS_R)
          vh = *reinterpret_cast<const float4*>(H + (size_t)grow * D + kc + q * 4);
      }
      *reinterpret_cast<float4*>(&a_s[r][q * 4]) = va;
      if constexpr (HAS_R) *reinterpret_cast<float4*>(&h_s[r][q * 4]) = vh;
    }
    // stage weight chunk: 32 x NCOLS
    for (int idx = tid; idx < 32 * (NCOLS / 4); idx += NT) {
      int kk = idx / (NCOLS / 4), c4 = idx % (NCOLS / 4);
      *reinterpret_cast<float4*>(&wl_s[kk][c4 * 4]) =
          *reinterpret_cast<const float4*>(WL + (size_t)(kc + kk) * NCOLS + c4 * 4);
      if constexpr (HAS_R)
        *reinterpret_cast<float4*>(&wr_s[kk][c4 * 4]) =
            *reinterpret_cast<const float4*>(WR + (size_t)(kc + kk) * NCOLS + c4 * 4);
    }
    __syncthreads();

#pragma unroll 4
    for (int k = 0; k < 32; ++k) {
      float wl[8], wr[8];
      const float4* wlr = reinterpret_cast<const float4*>(&wl_s[k][0]);
      float4 w0 = wlr[cg * 2], w1 = wlr[cg * 2 + 1];
      wl[0] = w0.x; wl[1] = w0.y; wl[2] = w0.z; wl[3] = w0.w;
      wl[4] = w1.x; wl[5] = w1.y; wl[6] = w1.z; wl[7] = w1.w;
      if constexpr (HAS_R) {
        const float4* wrr = reinterpret_cast<const float4*>(&wr_s[k][0]);
        float4 u0 = wrr[cg * 2], u1 = wrr[cg * 2 + 1];
        wr[0] = u0.x; wr[1] = u0.y; wr[2] = u0.z; wr[3] = u0.w;
        wr[4] = u1.x; wr[5] = u1.y; wr[6] = u1.z; wr[7] = u1.w;
      }
#pragma unroll
      for (int i = 0; i < 4; i++) {
        float av = a_s[rg * 4 + i][k];
        float hv = 0.f;
        if constexpr (HAS_R) hv = h_s[rg * 4 + i][k];
#pragma unroll
        for (int j = 0; j < 8; j++) {
          acc[i][j] += av * wl[j];
          if constexpr (HAS_R) acc[i][j] += hv * wr[j];
        }
      }
    }
  }

  // epilogue
  float4 b0 = *reinterpret_cast<const float4*>(bias + c0);
  float4 b1 = *reinterpret_cast<const float4*>(bias + c0 + 4);
  float bl[8] = {b0.x, b0.y, b0.z, b0.w, b1.x, b1.y, b1.z, b1.w};
#pragma unroll
  for (int i = 0; i < 4; i++) {
    int grow = row0 + rg * 4 + i;
    if (grow < N_NODES) {
      float o[8];
#pragma unroll
      for (int j = 0; j < 8; j++) {
        float v = acc[i][j] + bl[j];
        o[j] = RELU ? fmaxf(v, 0.f) : v;
      }
      float4 o0 = make_float4(o[0], o[1], o[2], o[3]);
      float4 o1 = make_float4(o[4], o[5], o[6], o[7]);
      *reinterpret_cast<float4*>(out + (size_t)grow * NCOLS + c0) = o0;
      *reinterpret_cast<float4*>(out + (size_t)grow * NCOLS + c0 + 4) = o1;
    }
  }
}

// ---------------- launch ----------------

extern "C" void kernel_launch(void* const* d_in, const int* in_sizes, int n_in,
                              void* d_out, int out_size, void* d_ws, size_t ws_size,
                              hipStream_t stream) {
  const float* x = (const float*)d_in[0];
  const int* edge = (const int*)d_in[1];
  const int* src = edge;
  const int* dst = edge + N_EDGES;
  const float* Wl0 = (const float*)d_in[2];
  const float* bl0 = (const float*)d_in[3];
  const float* Wr0 = (const float*)d_in[4];
  const float* Wl1 = (const float*)d_in[5];
  const float* bl1 = (const float*)d_in[6];
  const float* Wr1 = (const float*)d_in[7];
  const float* Wl2 = (const float*)d_in[8];
  const float* bl2 = (const float*)d_in[9];
  const float* Wr2 = (const float*)d_in[10];
  const float* W = (const float*)d_in[11];
  const float* b = (const float*)d_in[12];
  float* out = (float*)d_out;

  char* ws = (char*)d_ws;
  int* deg = (int*)(ws + 0);                       // 400 KB
  int* row_ptr = (int*)(ws + (1ll << 20));         // 400 KB + 4
  int* cursor = (int*)(ws + (2ll << 20));          // 400 KB
  float* inv_deg = (float*)(ws + (3ll << 20));     // 400 KB
  int* csr_src = (int*)(ws + (4ll << 20));         // 6.4 MB
  float* agg = (float*)(ws + (16ll << 20));        // 51.2 MB
  float* h_ws = (float*)(ws + (72ll << 20));       // 51.2 MB
  (void)ws_size; (void)n_in; (void)in_sizes; (void)out_size;

  hipMemsetAsync(deg, 0, N_NODES * sizeof(int), stream);
  deg_kernel<<<N_EDGES / 256, 256, 0, stream>>>(dst, deg);
  scan_kernel<<<1, 1024, 0, stream>>>(deg, row_ptr, cursor, inv_deg);
  fill_kernel<<<N_EDGES / 256, 256, 0, stream>>>(src, dst, cursor, csr_src);

  const int agg_grid = (N_NODES + 7) / 8;
  const int gemm_grid = (N_NODES + 63) / 64;

  // layer 0: mean(x) @ Wl0 + x @ Wr0 + bl0, relu -> h_ws
  agg_kernel<<<agg_grid, 256, 0, stream>>>(x, row_ptr, csr_src, inv_deg, agg);
  gemm_kernel<128, true, true><<<gemm_grid, 256, 0, stream>>>(agg, x, Wl0, Wr0, bl0, h_ws);
  // layer 1 (in-place on h_ws)
  agg_kernel<<<agg_grid, 256, 0, stream>>>(h_ws, row_ptr, csr_src, inv_deg, agg);
  gemm_kernel<128, true, true><<<gemm_grid, 256, 0, stream>>>(agg, h_ws, Wl1, Wr1, bl1, h_ws);
  // layer 2 (in-place on h_ws)
  agg_kernel<<<agg_grid, 256, 0, stream>>>(h_ws, row_ptr, csr_src, inv_deg, agg);
  gemm_kernel<128, true, true><<<gemm_grid, 256, 0, stream>>>(agg, h_ws, Wl2, Wr2, bl2, h_ws);
  // final: h_ws @ W + b -> out
  gemm_kernel<64, false, false><<<gemm_grid, 128, 0, stream>>>(h_ws, nullptr, W, nullptr, b, out);
}

// Round 2
// 867.262 us; speedup vs baseline: 1.1687x; 1.1687x over previous
//
#include <hip/hip_runtime.h>
#include <cstddef>

#define N_NODES 100000
#define N_EDGES 1600000
#define D 128

typedef unsigned int u32;
typedef unsigned long long u64;
typedef float f32x4 __attribute__((ext_vector_type(4)));
typedef __bf16 bf16x8 __attribute__((ext_vector_type(8)));

__device__ inline u32 f2bf(float f) {  // f32 -> bf16 bits (RTNE)
  u32 u = __builtin_bit_cast(u32, f);
  return (u + 0x7FFFu + ((u >> 16) & 1u)) >> 16;
}
__device__ inline float bf2f(u32 b) { return __builtin_bit_cast(float, b << 16); }
__device__ inline float recon(u32 p) {  // packed (hi<<16)|lo -> f32
  return __builtin_bit_cast(float, p & 0xFFFF0000u) + __builtin_bit_cast(float, p << 16);
}
__device__ inline u32 pack2(float v) {
  u32 hi = f2bf(v);
  u32 lo = f2bf(v - bf2f(hi));
  return (hi << 16) | lo;
}
__device__ inline bf16x8 mk_frag(u64 q0, u64 q1) {
  union { u64 q[2]; bf16x8 v; } u;
  u.q[0] = q0; u.q[1] = q1;
  return u.v;
}

// ---------------- graph structure ----------------

__global__ __launch_bounds__(256) void deg_kernel(const int* __restrict__ dst,
                                                  int* __restrict__ deg) {
  int e = blockIdx.x * 256 + threadIdx.x;
  if (e < N_EDGES) atomicAdd(&deg[dst[e]], 1);
}

__global__ __launch_bounds__(1024) void scan_kernel(const int* __restrict__ deg,
                                                    int* __restrict__ row_ptr,
                                                    int* __restrict__ cursor,
                                                    float* __restrict__ inv_deg) {
  __shared__ int buf[1024];
  __shared__ int carry_s;
  if (threadIdx.x == 0) carry_s = 0;
  __syncthreads();
  const int n = N_NODES;
  for (int base = 0; base < n; base += 4096) {
    int i0 = base + threadIdx.x * 4;
    int v[4];
#pragma unroll
    for (int j = 0; j < 4; j++) {
      int i = i0 + j;
      v[j] = (i < n) ? deg[i] : 0;
    }
    int s = v[0] + v[1] + v[2] + v[3];
    buf[threadIdx.x] = s;
    int acc = s;
    __syncthreads();
    for (int off = 1; off < 1024; off <<= 1) {
      int t = (threadIdx.x >= off) ? buf[threadIdx.x - off] : 0;
      __syncthreads();
      acc += t;
      buf[threadIdx.x] = acc;
      __syncthreads();
    }
    int carry = carry_s;
    int run = carry + acc - s;
#pragma unroll
    for (int j = 0; j < 4; j++) {
      int i = i0 + j;
      if (i < n) {
        row_ptr[i] = run;
        cursor[i] = run;
        inv_deg[i] = 1.0f / fmaxf((float)v[j], 1.0f);
        run += v[j];
      }
    }
    __syncthreads();
    if (threadIdx.x == 1023) carry_s = carry + acc;
    __syncthreads();
  }
  if (threadIdx.x == 0) row_ptr[n] = carry_s;
}

__global__ __launch_bounds__(256) void fill_kernel(const int* __restrict__ src,
                                                   const int* __restrict__ dst,
                                                   int* __restrict__ cursor,
                                                   int* __restrict__ csr_src) {
  int e = blockIdx.x * 256 + threadIdx.x;
  if (e < N_EDGES) {
    int pos = atomicAdd(&cursor[dst[e]], 1);
    csr_src[pos] = src[e];
  }
}

// ---------------- weight conversion: fp32 [K][C] -> transposed bf16 hi/lo planes [C][K]
// planes packed back-to-back: m in 0..5 are 128x128 at offset m*16384; m=6 is [64][128] at 98304.

__global__ __launch_bounds__(256) void convert_w_all(
    const float* __restrict__ w0, const float* __restrict__ w1, const float* __restrict__ w2,
    const float* __restrict__ w3, const float* __restrict__ w4, const float* __restrict__ w5,
    const float* __restrict__ w6,
    unsigned short* __restrict__ t_hi, unsigned short* __restrict__ t_lo) {
  int i = blockIdx.x * 256 + threadIdx.x;
  const int TOT = 6 * 16384 + 8192;
  if (i >= TOT) return;
  const float* w;
  int j, C;
  if (i < 6 * 16384) {
    int m = i >> 14; j = i & 16383; C = 128;
    w = (m == 0) ? w0 : (m == 1) ? w1 : (m == 2) ? w2 : (m == 3) ? w3 : (m == 4) ? w4 : w5;
  } else {
    j = i - 6 * 16384; C = 64; w = w6;
  }
  int k = j & 127;  // K always 128
  int c = j >> 7;
  float v = w[k * C + c];
  u32 hi = f2bf(v);
  u32 lo = f2bf(v - bf2f(hi));
  t_hi[i] = (unsigned short)hi;
  t_lo[i] = (unsigned short)lo;
}

// ---------------- aggregation: mean of neighbor rows; output split bf16 hi/lo planes
// one node per 32 lanes, 16 B/lane, neighbor loop unrolled x4 for MLP.

template <bool PACKED>
__global__ __launch_bounds__(256) void agg_kernel(
    const void* __restrict__ hsrc, const int* __restrict__ row_ptr,
    const int* __restrict__ csr_src, const float* __restrict__ inv_deg,
    unsigned short* __restrict__ out_hi, unsigned short* __restrict__ out_lo) {
  int node = blockIdx.x * 8 + (threadIdx.x >> 5);
  if (node >= N_NODES) return;
  int lane = threadIdx.x & 31;
  int p0 = row_ptr[node], p1 = row_ptr[node + 1];
  float a0 = 0.f, a1 = 0.f, a2 = 0.f, a3 = 0.f;
  int p = p0;
  if constexpr (PACKED) {
    const u32* h = (const u32*)hsrc;
    for (; p + 4 <= p1; p += 4) {
      int s0 = csr_src[p], s1 = csr_src[p + 1], s2 = csr_src[p + 2], s3 = csr_src[p + 3];
      uint4 v0 = *(const uint4*)(h + (size_t)s0 * D + lane * 4);
      uint4 v1 = *(const uint4*)(h + (size_t)s1 * D + lane * 4);
      uint4 v2 = *(const uint4*)(h + (size_t)s2 * D + lane * 4);
      uint4 v3 = *(const uint4*)(h + (size_t)s3 * D + lane * 4);
      a0 += recon(v0.x) + recon(v1.x) + recon(v2.x) + recon(v3.x);
      a1 += recon(v0.y) + recon(v1.y) + recon(v2.y) + recon(v3.y);
      a2 += recon(v0.z) + recon(v1.z) + recon(v2.z) + recon(v3.z);
      a3 += recon(v0.w) + recon(v1.w) + recon(v2.w) + recon(v3.w);
    }
    for (; p < p1; ++p) {
      int s = csr_src[p];
      uint4 v = *(const uint4*)(h + (size_t)s * D + lane * 4);
      a0 += recon(v.x); a1 += recon(v.y); a2 += recon(v.z); a3 += recon(v.w);
    }
  } else {
    const float* h = (const float*)hsrc;
    for (; p + 4 <= p1; p += 4) {
      int s0 = csr_src[p], s1 = csr_src[p + 1], s2 = csr_src[p + 2], s3 = csr_src[p + 3];
      float4 v0 = *(const float4*)(h + (size_t)s0 * D + lane * 4);
      float4 v1 = *(const float4*)(h + (size_t)s1 * D + lane * 4);
      float4 v2 = *(const float4*)(h + (size_t)s2 * D + lane * 4);
      float4 v3 = *(const float4*)(h + (size_t)s3 * D + lane * 4);
      a0 += v0.x + v1.x + v2.x + v3.x;
      a1 += v0.y + v1.y + v2.y + v3.y;
      a2 += v0.z + v1.z + v2.z + v3.z;
      a3 += v0.w + v1.w + v2.w + v3.w;
    }
    for (; p < p1; ++p) {
      int s = csr_src[p];
      float4 v = *(const float4*)(h + (size_t)s * D + lane * 4);
      a0 += v.x; a1 += v.y; a2 += v.z; a3 += v.w;
    }
  }
  float sc = inv_deg[node];
  a0 *= sc; a1 *= sc; a2 *= sc; a3 *= sc;
  u32 h0 = f2bf(a0), h1 = f2bf(a1), h2 = f2bf(a2), h3 = f2bf(a3);
  u32 l0 = f2bf(a0 - bf2f(h0)), l1 = f2bf(a1 - bf2f(h1));
  u32 l2 = f2bf(a2 - bf2f(h2)), l3 = f2bf(a3 - bf2f(h3));
  u64 hq = (u64)(h0 | (h1 << 16)) | (((u64)(h2 | (h3 << 16))) << 32);
  u64 lq = (u64)(l0 | (l1 << 16)) | (((u64)(l2 | (l3 << 16))) << 32);
  *(u64*)(out_hi + (size_t)node * D + lane * 4) = hq;
  *(u64*)(out_lo + (size_t)node * D + lane * 4) = lq;
}

// ---------------- MFMA GEMM: out = [relu]( A@WL (+ H@WR) + bias ), split-bf16 3-term
// 128x128 block tile, 4 waves (2x2), wave tile 64 x (NCOLS/2).
// LDS rows: 8 data u64 (32 bf16) + 1 pad u64 -> 72 B stride, conflict-free b64 frag reads.
// AFMT: 0 = split hi/lo bf16 planes, 1 = packed u32.  HFMT: 0 = packed u32, 1 = f32.

template <int NCOLS, int AFMT, bool HAS_R, int HFMT, bool OUT_F32>
__global__ __launch_bounds__(256, 2) void mfma_gemm(
    const unsigned short* __restrict__ A_hi, const unsigned short* __restrict__ A_lo,
    const u32* __restrict__ A_pk,
    const u32* __restrict__ H_pk, const float* __restrict__ H_f32,
    const unsigned short* __restrict__ WL_hi, const unsigned short* __restrict__ WL_lo,
    const unsigned short* __restrict__ WR_hi, const unsigned short* __restrict__ WR_lo,
    const float* __restrict__ bias, void* __restrict__ outp) {
  constexpr int CT = NCOLS / 32;
  __shared__ u64 sAh[128][9], sAl[128][9];
  __shared__ u64 sHh[HAS_R ? 128 : 1][HAS_R ? 9 : 1], sHl[HAS_R ? 128 : 1][HAS_R ? 9 : 1];
  __shared__ u64 sLh[NCOLS][9], sLl[NCOLS][9];
  __shared__ u64 sRh[HAS_R ? NCOLS : 1][HAS_R ? 9 : 1], sRl[HAS_R ? NCOLS : 1][HAS_R ? 9 : 1];

  const int tid = threadIdx.x;
  const int row0 = blockIdx.x * 128;
  const int lane = tid & 63;
  const int w = tid >> 6;
  const int wr = w >> 1, wc = w & 1;
  const int lrow = lane & 15, kb = lane >> 4;

  f32x4 acc[4][CT];
#pragma unroll
  for (int i = 0; i < 4; i++)
#pragma unroll
    for (int j = 0; j < CT; j++) acc[i][j] = (f32x4){0.f, 0.f, 0.f, 0.f};

  for (int kc = 0; kc < D; kc += 32) {
    __syncthreads();
    // ---- stage A
    if constexpr (AFMT == 0) {
      for (int idx = tid; idx < 128 * 4; idx += 256) {
        int r = idx >> 2, q = idx & 3;
        int g = row0 + r;
        u64 h0 = 0, h1 = 0, l0 = 0, l1 = 0;
        if (g < N_NODES) {
          const u64* ph = (const u64*)(A_hi + (size_t)g * D + kc + q * 8);
          const u64* pl = (const u64*)(A_lo + (size_t)g * D + kc + q * 8);
          h0 = ph[0]; h1 = ph[1]; l0 = pl[0]; l1 = pl[1];
        }
        sAh[r][q * 2] = h0; sAh[r][q * 2 + 1] = h1;
        sAl[r][q * 2] = l0; sAl[r][q * 2 + 1] = l1;
      }
    } else {
      for (int idx = tid; idx < 128 * 8; idx += 256) {
        int r = idx >> 3, q = idx & 7;
        int g = row0 + r;
        uint4 u = make_uint4(0, 0, 0, 0);
        if (g < N_NODES) u = *(const uint4*)(A_pk + (size_t)g * D + kc + q * 4);
        u32 hw0 = (u.x >> 16) | (u.y & 0xFFFF0000u);
        u32 hw1 = (u.z >> 16) | (u.w & 0xFFFF0000u);
        u32 lw0 = (u.x & 0xFFFFu) | (u.y << 16);
        u32 lw1 = (u.z & 0xFFFFu) | (u.w << 16);
        sAh[r][q] = ((u64)hw1 << 32) | hw0;
        sAl[r][q] = ((u64)lw1 << 32) | lw0;
      }
    }
    // ---- stage H
    if constexpr (HAS_R) {
      if constexpr (HFMT == 0) {
        for (int idx = tid; idx < 128 * 8; idx += 256) {
          int r = idx >> 3, q = idx & 7;
          int g = row0 + r;
          uint4 u = make_uint4(0, 0, 0, 0);
          if (g < N_NODES) u = *(const uint4*)(H_pk + (size_t)g * D + kc + q * 4);
          u32 hw0 = (u.x >> 16) | (u.y & 0xFFFF0000u);
          u32 hw1 = (u.z >> 16) | (u.w & 0xFFFF0000u);
          u32 lw0 = (u.x & 0xFFFFu) | (u.y << 16);
          u32 lw1 = (u.z & 0xFFFFu) | (u.w << 16);
          sHh[r][q] = ((u64)hw1 << 32) | hw0;
          sHl[r][q] = ((u64)lw1 << 32) | lw0;
        }
      } else {
        for (int idx = tid; idx < 128 * 8; idx += 256) {
          int r = idx >> 3, q = idx & 7;
          int g = row0 + r;
          float4 v = make_float4(0.f, 0.f, 0.f, 0.f);
          if (g < N_NODES) v = *(const float4*)(H_f32 + (size_t)g * D + kc + q * 4);
          u32 h0 = f2bf(v.x), h1 = f2bf(v.y), h2 = f2bf(v.z), h3 = f2bf(v.w);
          u32 l0 = f2bf(v.x - bf2f(h0)), l1 = f2bf(v.y - bf2f(h1));
          u32 l2 = f2bf(v.z - bf2f(h2)), l3 = f2bf(v.w - bf2f(h3));
          u32 hw0 = h0 | (h1 << 16), hw1 = h2 | (h3 << 16);
          u32 lw0 = l0 | (l1 << 16), lw1 = l2 | (l3 << 16);
          sHh[r][q] = ((u64)hw1 << 32) | hw0;
          sHl[r][q] = ((u64)lw1 << 32) | lw0;
        }
      }
    }
    // ---- stage W (pre-transposed bf16 planes [c][k])
    for (int idx = tid; idx < NCOLS * 4; idx += 256) {
      int c = idx >> 2, q = idx & 3;
      const u64* ph = (const u64*)(WL_hi + (size_t)c * D + kc + q * 8);
      const u64* pl = (const u64*)(WL_lo + (size_t)c * D + kc + q * 8);
      sLh[c][q * 2] = ph[0]; sLh[c][q * 2 + 1] = ph[1];
      sLl[c][q * 2] = pl[0]; sLl[c][q * 2 + 1] = pl[1];
      if constexpr (HAS_R) {
        const u64* qh = (const u64*)(WR_hi + (size_t)c * D + kc + q * 8);
        const u64* ql = (const u64*)(WR_lo + (size_t)c * D + kc + q * 8);
        sRh[c][q * 2] = qh[0]; sRh[c][q * 2 + 1] = qh[1];
        sRl[c][q * 2] = ql[0]; sRl[c][q * 2 + 1] = ql[1];
      }
    }
    __syncthreads();

    // ---- compute
    bf16x8 fAh[4], fAl[4], fHh[4], fHl[4];
#pragma unroll
    for (int rt = 0; rt < 4; ++rt) {
      int rr = wr * 64 + rt * 16 + lrow;
      fAh[rt] = mk_frag(sAh[rr][kb * 2], sAh[rr][kb * 2 + 1]);
      fAl[rt] = mk_frag(sAl[rr][kb * 2], sAl[rr][kb * 2 + 1]);
      if constexpr (HAS_R) {
        fHh[rt] = mk_frag(sHh[rr][kb * 2], sHh[rr][kb * 2 + 1]);
        fHl[rt] = mk_frag(sHl[rr][kb * 2], sHl[rr][kb * 2 + 1]);
      }
    }
#pragma unroll
    for (int ct = 0; ct < CT; ++ct) {
      int cc = wc * (NCOLS / 2) + ct * 16 + lrow;
      bf16x8 bLh = mk_frag(sLh[cc][kb * 2], sLh[cc][kb * 2 + 1]);
      bf16x8 bLl = mk_frag(sLl[cc][kb * 2], sLl[cc][kb * 2 + 1]);
      bf16x8 bRh = bLh, bRl = bLl;
      if constexpr (HAS_R) {
        bRh = mk_frag(sRh[cc][kb * 2], sRh[cc][kb * 2 + 1]);
        bRl = mk_frag(sRl[cc][kb * 2], sRl[cc][kb * 2 + 1]);
      }
#pragma unroll
      for (int rt = 0; rt < 4; ++rt) {
        acc[rt][ct] = __builtin_amdgcn_mfma_f32_16x16x32_bf16(fAh[rt], bLh, acc[rt][ct], 0, 0, 0);
        acc[rt][ct] = __builtin_amdgcn_mfma_f32_16x16x32_bf16(fAl[rt], bLh, acc[rt][ct], 0, 0, 0);
        acc[rt][ct] = __builtin_amdgcn_mfma_f32_16x16x32_bf16(fAh[rt], bLl, acc[rt][ct], 0, 0, 0);
        if constexpr (HAS_R) {
          acc[rt][ct] = __builtin_amdgcn_mfma_f32_16x16x32_bf16(fHh[rt], bRh, acc[rt][ct], 0, 0, 0);
          acc[rt][ct] = __builtin_amdgcn_mfma_f32_16x16x32_bf16(fHl[rt], bRh, acc[rt][ct], 0, 0, 0);
          acc[rt][ct] = __builtin_amdgcn_mfma_f32_16x16x32_bf16(fHh[rt], bRl, acc[rt][ct], 0, 0, 0);
        }
      }
    }
  }

  // ---- epilogue: bias (+relu), pack or f32 store
#pragma unroll
  for (int ct = 0; ct < CT; ++ct) {
    int col = wc * (NCOLS / 2) + ct * 16 + lrow;
    float bv = bias[col];
#pragma unroll
    for (int rt = 0; rt < 4; ++rt) {
#pragma unroll
      for (int r = 0; r < 4; ++r) {
        int g = row0 + wr * 64 + rt * 16 + kb * 4 + r;
        if (g < N_NODES) {
          float v = acc[rt][ct][r] + bv;
          if constexpr (OUT_F32) {
            ((float*)outp)[(size_t)g * NCOLS + col] = v;
          } else {
            ((u32*)outp)[(size_t)g * D + col] = pack2(fmaxf(v, 0.f));
          }
        }
      }
    }
  }
}

// ---------------- launch ----------------

extern "C" void kernel_launch(void* const* d_in, const int* in_sizes, int n_in,
                              void* d_out, int out_size, void* d_ws, size_t ws_size,
                              hipStream_t stream) {
  const float* x = (const float*)d_in[0];
  const int* edge = (const int*)d_in[1];
  const int* src = edge;
  const int* dst = edge + N_EDGES;
  const float* Wl0 = (const float*)d_in[2];
  const float* bl0 = (const float*)d_in[3];
  const float* Wr0 = (const float*)d_in[4];
  const float* Wl1 = (const float*)d_in[5];
  const float* bl1 = (const float*)d_in[6];
  const float* Wr1 = (const float*)d_in[7];
  const float* Wl2 = (const float*)d_in[8];
  const float* bl2 = (const float*)d_in[9];
  const float* Wr2 = (const float*)d_in[10];
  const float* W = (const float*)d_in[11];
  const float* b = (const float*)d_in[12];
  float* out = (float*)d_out;
  (void)ws_size; (void)n_in; (void)in_sizes; (void)out_size;

  char* ws = (char*)d_ws;
  int* deg = (int*)(ws);
  int* row_ptr = (int*)(ws + (1ll << 20));
  int* cursor = (int*)(ws + (2ll << 20));
  float* inv_deg = (float*)(ws + (3ll << 20));
  int* csr_src = (int*)(ws + (4ll << 20));                     // 6.4 MB
  unsigned short* wt_hi = (unsigned short*)(ws + (11ll << 20));  // 213 KB
  unsigned short* wt_lo = (unsigned short*)(ws + (12ll << 20));
  unsigned short* agg_hi = (unsigned short*)(ws + (13ll << 20)); // 25.6 MB
  unsigned short* agg_lo = (unsigned short*)(ws + (40ll << 20)); // 25.6 MB
  u32* hp = (u32*)(ws + (68ll << 20));                          // 51.2 MB -> ends at 119.2 MB

  hipMemsetAsync(deg, 0, N_NODES * sizeof(int), stream);
  deg_kernel<<<N_EDGES / 256, 256, 0, stream>>>(dst, deg);
  scan_kernel<<<1, 1024, 0, stream>>>(deg, row_ptr, cursor, inv_deg);
  fill_kernel<<<N_EDGES / 256, 256, 0, stream>>>(src, dst, cursor, csr_src);
  convert_w_all<<<(6 * 16384 + 8192 + 255) / 256, 256, 0, stream>>>(
      Wl0, Wr0, Wl1, Wr1, Wl2, Wr2, W, wt_hi, wt_lo);

  const int agg_grid = (N_NODES + 7) / 8;
  const int gemm_grid = (N_NODES + 127) / 128;
  const int PW = 16384;

  // layer 0
  agg_kernel<false><<<agg_grid, 256, 0, stream>>>(x, row_ptr, csr_src, inv_deg, agg_hi, agg_lo);
  mfma_gemm<128, 0, true, 1, false><<<gemm_grid, 256, 0, stream>>>(
      agg_hi, agg_lo, nullptr, nullptr, x,
      wt_hi + 0 * PW, wt_lo + 0 * PW, wt_hi + 1 * PW, wt_lo + 1 * PW, bl0, hp);
  // layer 1
  agg_kernel<true><<<agg_grid, 256, 0, stream>>>(hp, row_ptr, csr_src, inv_deg, agg_hi, agg_lo);
  mfma_gemm<128, 0, true, 0, false><<<gemm_grid, 256, 0, stream>>>(
      agg_hi, agg_lo, nullptr, hp, nullptr,
      wt_hi + 2 * PW, wt_lo + 2 * PW, wt_hi + 3 * PW, wt_lo + 3 * PW, bl1, hp);
  // layer 2
  agg_kernel<true><<<agg_grid, 256, 0, stream>>>(hp, row_ptr, csr_src, inv_deg, agg_hi, agg_lo);
  mfma_gemm<128, 0, true, 0, false><<<gemm_grid, 256, 0, stream>>>(
      agg_hi, agg_lo, nullptr, hp, nullptr,
      wt_hi + 4 * PW, wt_lo + 4 * PW, wt_hi + 5 * PW, wt_lo + 5 * PW, bl2, hp);
  // final projection
  mfma_gemm<64, 1, false, 0, true><<<gemm_grid, 256, 0, stream>>>(
      nullptr, nullptr, hp, nullptr, nullptr,
      wt_hi + 6 * PW, wt_lo + 6 * PW, nullptr, nullptr, b, out);
}

// Round 3
// 403.353 us; speedup vs baseline: 2.5129x; 2.1501x over previous
//
#include <hip/hip_runtime.h>
#include <cstddef>

#define N_NODES 100000
#define N_EDGES 1600000
#define D 128
#define NB 782          // ceil(N_NODES/128) buckets of 128 dst nodes
#define NBLK 128        // binning blocks
#define CHUNK 12500     // N_EDGES / NBLK

typedef unsigned int u32;
typedef unsigned long long u64;
typedef float f32x4 __attribute__((ext_vector_type(4)));
typedef _Float16 f16x8 __attribute__((ext_vector_type(8)));

__device__ inline f16x8 mk16(u64 a, u64 b) {
  union { u64 q[2]; f16x8 v; } u;
  u.q[0] = a; u.q[1] = b;
  return u.v;
}

// ---------------- graph build: bucketed counting-sort CSR ----------------

__global__ __launch_bounds__(256) void k_count(const int* __restrict__ dst,
                                               int* __restrict__ g_cnt) {
  __shared__ int cnt[NB];
  for (int i = threadIdx.x; i < NB; i += 256) cnt[i] = 0;
  __syncthreads();
  int e0 = blockIdx.x * CHUNK;
  for (int e = e0 + threadIdx.x; e < e0 + CHUNK; e += 256)
    atomicAdd(&cnt[dst[e] >> 7], 1);
  __syncthreads();
  for (int i = threadIdx.x; i < NB; i += 256)
    if (cnt[i]) atomicAdd(&g_cnt[i], cnt[i]);
}

__global__ __launch_bounds__(1024) void k_scan(const int* __restrict__ g_cnt,
                                               int* __restrict__ bucket_base,
                                               int* __restrict__ bucket_cur,
                                               int* __restrict__ row_ptr) {
  __shared__ int sb[1024];
  int tid = threadIdx.x;
  int v = (tid < NB) ? g_cnt[tid] : 0;
  sb[tid] = v;
  __syncthreads();
  for (int off = 1; off < 1024; off <<= 1) {
    int t = (tid >= off) ? sb[tid - off] : 0;
    __syncthreads();
    sb[tid] += t;
    __syncthreads();
  }
  int excl = sb[tid] - v;
  if (tid < NB) { bucket_base[tid] = excl; bucket_cur[tid] = excl; }
  if (tid == 0) { bucket_base[NB] = N_EDGES; row_ptr[N_NODES] = N_EDGES; }
}

__global__ __launch_bounds__(256) void k_scatter(const int* __restrict__ src,
                                                 const int* __restrict__ dst,
                                                 int* __restrict__ bucket_cur,
                                                 u32* __restrict__ binned) {
  __shared__ int cnt[NB];
  __shared__ int base[NB];
  for (int i = threadIdx.x; i < NB; i += 256) cnt[i] = 0;
  __syncthreads();
  int e0 = blockIdx.x * CHUNK;
  for (int e = e0 + threadIdx.x; e < e0 + CHUNK; e += 256)
    atomicAdd(&cnt[dst[e] >> 7], 1);
  __syncthreads();
  for (int i = threadIdx.x; i < NB; i += 256) {
    int c = cnt[i];
    base[i] = c ? atomicAdd(&bucket_cur[i], c) : 0;
  }
  __syncthreads();
  for (int i = threadIdx.x; i < NB; i += 256) cnt[i] = 0;
  __syncthreads();
  for (int e = e0 + threadIdx.x; e < e0 + CHUNK; e += 256) {
    int d = dst[e];
    int b = d >> 7;
    int pos = base[b] + atomicAdd(&cnt[b], 1);
    binned[pos] = ((u32)(d & 127) << 17) | (u32)src[e];
  }
}

__global__ __launch_bounds__(256) void k_build(const u32* __restrict__ binned,
                                               const int* __restrict__ bucket_base,
                                               int* __restrict__ row_ptr,
                                               float* __restrict__ inv_deg,
                                               int* __restrict__ csr_src) {
  __shared__ int deg[128], sc[128], cur[128];
  int b = blockIdx.x;
  int tid = threadIdx.x;
  int nbase = b << 7;
  int e0 = bucket_base[b], e1 = bucket_base[b + 1];
  if (tid < 128) deg[tid] = 0;
  __syncthreads();
  for (int e = e0 + tid; e < e1; e += 256)
    atomicAdd(&deg[binned[e] >> 17], 1);
  __syncthreads();
  int dv = (tid < 128) ? deg[tid] : 0;
  if (tid < 128) sc[tid] = dv;
  __syncthreads();
  for (int off = 1; off < 128; off <<= 1) {
    int t = (tid >= off && tid < 128) ? sc[tid - off] : 0;
    __syncthreads();
    if (tid < 128) sc[tid] += t;
    __syncthreads();
  }
  if (tid < 128) {
    int excl = sc[tid] - dv;
    cur[tid] = excl;
    int node = nbase + tid;
    if (node < N_NODES) {
      row_ptr[node] = e0 + excl;
      inv_deg[node] = 1.0f / fmaxf((float)dv, 1.0f);
    }
  }
  __syncthreads();
  for (int e = e0 + tid; e < e1; e += 256) {
    u32 w = binned[e];
    int dl = w >> 17;
    int pos = e0 + atomicAdd(&cur[dl], 1);
    csr_src[pos] = (int)(w & 0x1FFFFu);
  }
}

// ---------------- conversions ----------------

__global__ __launch_bounds__(256) void k_convert_x(const float* __restrict__ x,
                                                   unsigned short* __restrict__ x16) {
  size_t i = ((size_t)blockIdx.x * 256 + threadIdx.x) * 8;
  float4 v0 = *(const float4*)(x + i);
  float4 v1 = *(const float4*)(x + i + 4);
  f16x8 h;
  h[0] = (_Float16)v0.x; h[1] = (_Float16)v0.y; h[2] = (_Float16)v0.z; h[3] = (_Float16)v0.w;
  h[4] = (_Float16)v1.x; h[5] = (_Float16)v1.y; h[6] = (_Float16)v1.z; h[7] = (_Float16)v1.w;
  *(uint4*)(x16 + i) = __builtin_bit_cast(uint4, h);
}

// wt16 layout: layer l in 0..2 at l*32768: [s][c][k] (s=0 Wl^T, s=1 Wr^T), 128x128 each;
// final at 98304: [c][k], 64x128.
__global__ __launch_bounds__(256) void k_convert_w(
    const float* __restrict__ w0, const float* __restrict__ w1, const float* __restrict__ w2,
    const float* __restrict__ w3, const float* __restrict__ w4, const float* __restrict__ w5,
    const float* __restrict__ w6, unsigned short* __restrict__ wt16) {
  int i = blockIdx.x * 256 + threadIdx.x;
  const int TOT = 6 * 16384 + 8192;
  if (i >= TOT) return;
  float v;
  if (i < 6 * 16384) {
    int m = i >> 14;  // 0..5 -> Wl0,Wr0,Wl1,Wr1,Wl2,Wr2
    int j = i & 16383;
    int c = j >> 7, k = j & 127;
    const float* w = (m == 0) ? w0 : (m == 1) ? w1 : (m == 2) ? w2
                   : (m == 3) ? w3 : (m == 4) ? w4 : w5;
    v = w[k * 128 + c];
  } else {
    int j = i - 6 * 16384;
    int c = j >> 7, k = j & 127;
    v = w6[k * 64 + c];
  }
  _Float16 h = (_Float16)v;
  wt16[i] = __builtin_bit_cast(unsigned short, h);
}

// ---------------- aggregation: mean of neighbor f16 rows ----------------
// 16 lanes per node (16B/lane), 4 neighbors in flight -> 16 rows in flight per wave.

__global__ __launch_bounds__(256) void k_agg(const unsigned short* __restrict__ h16,
                                             const int* __restrict__ row_ptr,
                                             const int* __restrict__ csr_src,
                                             const float* __restrict__ inv_deg,
                                             unsigned short* __restrict__ out16) {
  int node = blockIdx.x * 16 + (threadIdx.x >> 4);
  if (node >= N_NODES) return;
  int sub = threadIdx.x & 15;
  int p0 = row_ptr[node], p1 = row_ptr[node + 1];
  float a[8];
#pragma unroll
  for (int j = 0; j < 8; j++) a[j] = 0.f;
  int p = p0;
  for (; p + 4 <= p1; p += 4) {
    int s0 = csr_src[p], s1 = csr_src[p + 1], s2 = csr_src[p + 2], s3 = csr_src[p + 3];
    uint4 u0 = *(const uint4*)(h16 + (size_t)s0 * D + sub * 8);
    uint4 u1 = *(const uint4*)(h16 + (size_t)s1 * D + sub * 8);
    uint4 u2 = *(const uint4*)(h16 + (size_t)s2 * D + sub * 8);
    uint4 u3 = *(const uint4*)(h16 + (size_t)s3 * D + sub * 8);
    f16x8 h0 = __builtin_bit_cast(f16x8, u0), h1 = __builtin_bit_cast(f16x8, u1);
    f16x8 h2 = __builtin_bit_cast(f16x8, u2), h3 = __builtin_bit_cast(f16x8, u3);
#pragma unroll
    for (int j = 0; j < 8; j++)
      a[j] += (float)h0[j] + (float)h1[j] + (float)h2[j] + (float)h3[j];
  }
  for (; p < p1; ++p) {
    int s = csr_src[p];
    uint4 u = *(const uint4*)(h16 + (size_t)s * D + sub * 8);
    f16x8 h = __builtin_bit_cast(f16x8, u);
#pragma unroll
    for (int j = 0; j < 8; j++) a[j] += (float)h[j];
  }
  float sc = inv_deg[node];
  f16x8 o;
#pragma unroll
  for (int j = 0; j < 8; j++) o[j] = (_Float16)(a[j] * sc);
  *(uint4*)(out16 + (size_t)node * D + sub * 8) = __builtin_bit_cast(uint4, o);
}

// ---------------- MFMA GEMM: out = [relu]( sum_s in_s @ W_s + bias ) ----------------
// 128x128 block tile (NCOLS cols), 4 waves 2x2, f16 single plane, K chunked by 32.
// LDS rows: 8 u64 data + 1 pad -> 72B stride (16 distinct even banks, <=2-way on b64).

template <int NCOLS, int NSRC, bool RELU, bool OUTF16>
__global__ __launch_bounds__(256) void k_gemm(
    const unsigned short* __restrict__ in0, const unsigned short* __restrict__ in1,
    const unsigned short* __restrict__ wt, const float* __restrict__ bias,
    void* __restrict__ outp) {
  constexpr int CT = NCOLS / 32;
  __shared__ u64 sI[128][9];
  __shared__ u64 sW[NCOLS][9];

  const int tid = threadIdx.x;
  const int row0 = blockIdx.x * 128;
  const int lane = tid & 63;
  const int w = tid >> 6;
  const int wr = w >> 1, wc = w & 1;
  const int lrow = lane & 15, kb = lane >> 4;

  f32x4 acc[4][CT];
#pragma unroll
  for (int i = 0; i < 4; i++)
#pragma unroll
    for (int j = 0; j < CT; j++) acc[i][j] = (f32x4){0.f, 0.f, 0.f, 0.f};

#pragma unroll
  for (int s = 0; s < NSRC; ++s) {
    const unsigned short* inP = s ? in1 : in0;
    const unsigned short* wP = wt + (size_t)s * NCOLS * D;
#pragma unroll
    for (int kc = 0; kc < D; kc += 32) {
      __syncthreads();
      for (int idx = tid; idx < 512; idx += 256) {
        int r = idx >> 2, q = idx & 3;
        int g = row0 + r;
        u64 a = 0, b = 0;
        if (g < N_NODES) {
          const u64* pp = (const u64*)(inP + (size_t)g * D + kc + q * 8);
          a = pp[0]; b = pp[1];
        }
        sI[r][q * 2] = a; sI[r][q * 2 + 1] = b;
      }
      for (int idx = tid; idx < NCOLS * 4; idx += 256) {
        int c = idx >> 2, q = idx & 3;
        const u64* pp = (const u64*)(wP + (size_t)c * D + kc + q * 8);
        sW[c][q * 2] = pp[0]; sW[c][q * 2 + 1] = pp[1];
      }
      __syncthreads();

      f16x8 fA[4], fB[CT];
#pragma unroll
      for (int rt = 0; rt < 4; ++rt) {
        int rr = wr * 64 + rt * 16 + lrow;
        fA[rt] = mk16(sI[rr][kb * 2], sI[rr][kb * 2 + 1]);
      }
#pragma unroll
      for (int ct = 0; ct < CT; ++ct) {
        int cc = wc * (NCOLS / 2) + ct * 16 + lrow;
        fB[ct] = mk16(sW[cc][kb * 2], sW[cc][kb * 2 + 1]);
      }
#pragma unroll
      for (int ct = 0; ct < CT; ++ct)
#pragma unroll
        for (int rt = 0; rt < 4; ++rt)
          acc[rt][ct] = __builtin_amdgcn_mfma_f32_16x16x32_f16(fA[rt], fB[ct], acc[rt][ct], 0, 0, 0);
    }
  }

#pragma unroll
  for (int ct = 0; ct < CT; ++ct) {
    int col = wc * (NCOLS / 2) + ct * 16 + lrow;
    float bv = bias[col];
#pragma unroll
    for (int rt = 0; rt < 4; ++rt) {
#pragma unroll
      for (int r = 0; r < 4; ++r) {
        int g = row0 + wr * 64 + rt * 16 + kb * 4 + r;
        if (g < N_NODES) {
          float v = acc[rt][ct][r] + bv;
          if (RELU) v = fmaxf(v, 0.f);
          if constexpr (OUTF16) {
            _Float16 hv = (_Float16)v;
            ((unsigned short*)outp)[(size_t)g * NCOLS + col] =
                __builtin_bit_cast(unsigned short, hv);
          } else {
            ((float*)outp)[(size_t)g * NCOLS + col] = v;
          }
        }
      }
    }
  }
}

// ---------------- launch ----------------

extern "C" void kernel_launch(void* const* d_in, const int* in_sizes, int n_in,
                              void* d_out, int out_size, void* d_ws, size_t ws_size,
                              hipStream_t stream) {
  const float* x = (const float*)d_in[0];
  const int* edge = (const int*)d_in[1];
  const int* src = edge;
  const int* dst = edge + N_EDGES;
  const float* Wl0 = (const float*)d_in[2];
  const float* bl0 = (const float*)d_in[3];
  const float* Wr0 = (const float*)d_in[4];
  const float* Wl1 = (const float*)d_in[5];
  const float* bl1 = (const float*)d_in[6];
  const float* Wr1 = (const float*)d_in[7];
  const float* Wl2 = (const float*)d_in[8];
  const float* bl2 = (const float*)d_in[9];
  const float* Wr2 = (const float*)d_in[10];
  const float* W = (const float*)d_in[11];
  const float* b = (const float*)d_in[12];
  float* out = (float*)d_out;
  (void)ws_size; (void)n_in; (void)in_sizes; (void)out_size;

  char* ws = (char*)d_ws;
  int* g_cnt = (int*)(ws);                              // NB ints
  int* bucket_base = (int*)(ws + (16ll << 10));         // NB+1
  int* bucket_cur = (int*)(ws + (32ll << 10));          // NB
  int* row_ptr = (int*)(ws + (64ll << 10));             // N+1
  float* inv_deg = (float*)(ws + (576ll << 10));        // N
  int* csr_src = (int*)(ws + (1ll << 20));              // 6.4 MB
  u32* binned = (u32*)(ws + (8ll << 20));               // 6.4 MB
  unsigned short* wt16 = (unsigned short*)(ws + (15ll << 20));   // 208 KB
  unsigned short* x16 = (unsigned short*)(ws + (16ll << 20));    // 25.6 MB
  unsigned short* agg16 = (unsigned short*)(ws + (42ll << 20));  // 25.6 MB
  unsigned short* h16 = (unsigned short*)(ws + (68ll << 20));    // 25.6 MB -> ends ~94 MB

  hipMemsetAsync(g_cnt, 0, NB * sizeof(int), stream);
  k_count<<<NBLK, 256, 0, stream>>>(dst, g_cnt);
  k_scan<<<1, 1024, 0, stream>>>(g_cnt, bucket_base, bucket_cur, row_ptr);
  k_scatter<<<NBLK, 256, 0, stream>>>(src, dst, bucket_cur, binned);
  k_build<<<NB, 256, 0, stream>>>(binned, bucket_base, row_ptr, inv_deg, csr_src);
  k_convert_x<<<6250, 256, 0, stream>>>(x, x16);
  k_convert_w<<<(6 * 16384 + 8192 + 255) / 256, 256, 0, stream>>>(
      Wl0, Wr0, Wl1, Wr1, Wl2, Wr2, W, wt16);

  const int agg_grid = (N_NODES + 15) / 16;
  const int gemm_grid = (N_NODES + 127) / 128;

  // layer 0
  k_agg<<<agg_grid, 256, 0, stream>>>(x16, row_ptr, csr_src, inv_deg, agg16);
  k_gemm<128, 2, true, true><<<gemm_grid, 256, 0, stream>>>(agg16, x16, wt16 + 0, bl0, h16);
  // layer 1
  k_agg<<<agg_grid, 256, 0, stream>>>(h16, row_ptr, csr_src, inv_deg, agg16);
  k_gemm<128, 2, true, true><<<gemm_grid, 256, 0, stream>>>(agg16, h16, wt16 + 32768, bl1, h16);
  // layer 2
  k_agg<<<agg_grid, 256, 0, stream>>>(h16, row_ptr, csr_src, inv_deg, agg16);
  k_gemm<128, 2, true, true><<<gemm_grid, 256, 0, stream>>>(agg16, h16, wt16 + 65536, bl2, h16);
  // final projection (f32 out)
  k_gemm<64, 1, false, false><<<gemm_grid, 256, 0, stream>>>(h16, nullptr, wt16 + 98304, b, out);
}

// Round 4
// 345.045 us; speedup vs baseline: 2.9376x; 1.1690x over previous
//
#include <hip/hip_runtime.h>
#include <cstddef>

#define N_NODES 100000
#define N_EDGES 1600000
#define D 128
#define NB 782          // ceil(N_NODES/128) buckets of 128 dst nodes
#define CAP 3072        // fixed bucket capacity (mean 2046, sd ~45 -> huge headroom)
#define NBLK 512        // binning blocks
#define CHUNK 3125      // N_EDGES / NBLK

typedef unsigned int u32;
typedef unsigned long long u64;
typedef float f32x4 __attribute__((ext_vector_type(4)));
typedef _Float16 f16x8 __attribute__((ext_vector_type(8)));

__device__ inline f16x8 mk16(u64 a, u64 b) {
  union { u64 q[2]; f16x8 v; } u;
  u.q[0] = a; u.q[1] = b;
  return u.v;
}

// ---------------- graph build: fixed-capacity bucketed CSR ----------------

__global__ __launch_bounds__(256) void k_scatter(const int* __restrict__ src,
                                                 const int* __restrict__ dst,
                                                 int* __restrict__ bucket_cur,
                                                 u32* __restrict__ binned) {
  __shared__ int cnt[NB];
  __shared__ int base[NB];
  for (int i = threadIdx.x; i < NB; i += 256) cnt[i] = 0;
  __syncthreads();
  int e0 = blockIdx.x * CHUNK;
  for (int e = e0 + threadIdx.x; e < e0 + CHUNK; e += 256)
    atomicAdd(&cnt[dst[e] >> 7], 1);
  __syncthreads();
  for (int i = threadIdx.x; i < NB; i += 256) {
    int c = cnt[i];
    base[i] = c ? atomicAdd(&bucket_cur[i], c) : 0;
  }
  __syncthreads();
  for (int i = threadIdx.x; i < NB; i += 256) cnt[i] = 0;
  __syncthreads();
  for (int e = e0 + threadIdx.x; e < e0 + CHUNK; e += 256) {
    int d = dst[e];
    int b = d >> 7;
    int pos = base[b] + atomicAdd(&cnt[b], 1);
    binned[pos] = ((u32)(d & 127) << 17) | (u32)src[e];
  }
}

__global__ __launch_bounds__(256) void k_build(const u32* __restrict__ binned,
                                               const int* __restrict__ bucket_cur,
                                               int* __restrict__ row_start,
                                               int* __restrict__ row_end,
                                               float* __restrict__ inv_deg,
                                               int* __restrict__ csr_src) {
  __shared__ int deg[128], sc[128], cur[128];
  int b = blockIdx.x;
  int tid = threadIdx.x;
  int nbase = b << 7;
  int e0 = b * CAP, e1 = bucket_cur[b];
  if (tid < 128) deg[tid] = 0;
  __syncthreads();
  for (int e = e0 + tid; e < e1; e += 256)
    atomicAdd(&deg[binned[e] >> 17], 1);
  __syncthreads();
  int dv = (tid < 128) ? deg[tid] : 0;
  if (tid < 128) sc[tid] = dv;
  __syncthreads();
  for (int off = 1; off < 128; off <<= 1) {
    int t = (tid >= off && tid < 128) ? sc[tid - off] : 0;
    __syncthreads();
    if (tid < 128) sc[tid] += t;
    __syncthreads();
  }
  if (tid < 128) {
    int excl = sc[tid] - dv;
    cur[tid] = excl;
    int node = nbase + tid;
    if (node < N_NODES) {
      row_start[node] = e0 + excl;
      row_end[node] = e0 + excl + dv;
      inv_deg[node] = 1.0f / fmaxf((float)dv, 1.0f);
    }
  }
  __syncthreads();
  for (int e = e0 + tid; e < e1; e += 256) {
    u32 w = binned[e];
    int dl = w >> 17;
    int pos = e0 + atomicAdd(&cur[dl], 1);
    csr_src[pos] = (int)(w & 0x1FFFFu);
  }
}

// ---------------- conversions ----------------

__global__ __launch_bounds__(256) void k_convert_x(const float* __restrict__ x,
                                                   unsigned short* __restrict__ x16) {
  size_t i = ((size_t)blockIdx.x * 256 + threadIdx.x) * 8;
  float4 v0 = *(const float4*)(x + i);
  float4 v1 = *(const float4*)(x + i + 4);
  f16x8 h;
  h[0] = (_Float16)v0.x; h[1] = (_Float16)v0.y; h[2] = (_Float16)v0.z; h[3] = (_Float16)v0.w;
  h[4] = (_Float16)v1.x; h[5] = (_Float16)v1.y; h[6] = (_Float16)v1.z; h[7] = (_Float16)v1.w;
  *(uint4*)(x16 + i) = __builtin_bit_cast(uint4, h);
}

__global__ __launch_bounds__(256) void k_convert_w(
    const float* __restrict__ w0, const float* __restrict__ w1, const float* __restrict__ w2,
    const float* __restrict__ w3, const float* __restrict__ w4, const float* __restrict__ w5,
    const float* __restrict__ w6, unsigned short* __restrict__ wt16,
    int* __restrict__ bucket_cur) {
  int i = blockIdx.x * 256 + threadIdx.x;
  if (i < NB) bucket_cur[i] = i * CAP;
  const int TOT = 6 * 16384 + 8192;
  if (i >= TOT) return;
  float v;
  if (i < 6 * 16384) {
    int m = i >> 14;  // 0..5 -> Wl0,Wr0,Wl1,Wr1,Wl2,Wr2
    int j = i & 16383;
    int c = j >> 7, k = j & 127;
    const float* w = (m == 0) ? w0 : (m == 1) ? w1 : (m == 2) ? w2
                   : (m == 3) ? w3 : (m == 4) ? w4 : w5;
    v = w[k * 128 + c];
  } else {
    int j = i - 6 * 16384;
    int c = j >> 7, k = j & 127;
    v = w6[k * 64 + c];
  }
  _Float16 h = (_Float16)v;
  wt16[i] = __builtin_bit_cast(unsigned short, h);
}

// ---------------- aggregation: mean of neighbor f16 rows ----------------
// 16 lanes per node (16B/lane), neighbor loop unrolled x8 -> 32 rows in flight per wave.

__global__ __launch_bounds__(256) void k_agg(const unsigned short* __restrict__ h16,
                                             const int* __restrict__ row_start,
                                             const int* __restrict__ row_end,
                                             const float* __restrict__ inv_deg,
                                             const int* __restrict__ csr_src,
                                             unsigned short* __restrict__ out16) {
  int node = blockIdx.x * 16 + (threadIdx.x >> 4);
  if (node >= N_NODES) return;
  int sub = threadIdx.x & 15;
  int p0 = row_start[node], p1 = row_end[node];
  float a[8];
#pragma unroll
  for (int j = 0; j < 8; j++) a[j] = 0.f;
  int p = p0;
  for (; p + 8 <= p1; p += 8) {
    int s0 = csr_src[p], s1 = csr_src[p + 1], s2 = csr_src[p + 2], s3 = csr_src[p + 3];
    int s4 = csr_src[p + 4], s5 = csr_src[p + 5], s6 = csr_src[p + 6], s7 = csr_src[p + 7];
    uint4 u0 = *(const uint4*)(h16 + (size_t)s0 * D + sub * 8);
    uint4 u1 = *(const uint4*)(h16 + (size_t)s1 * D + sub * 8);
    uint4 u2 = *(const uint4*)(h16 + (size_t)s2 * D + sub * 8);
    uint4 u3 = *(const uint4*)(h16 + (size_t)s3 * D + sub * 8);
    uint4 u4 = *(const uint4*)(h16 + (size_t)s4 * D + sub * 8);
    uint4 u5 = *(const uint4*)(h16 + (size_t)s5 * D + sub * 8);
    uint4 u6 = *(const uint4*)(h16 + (size_t)s6 * D + sub * 8);
    uint4 u7 = *(const uint4*)(h16 + (size_t)s7 * D + sub * 8);
    f16x8 h0 = __builtin_bit_cast(f16x8, u0), h1 = __builtin_bit_cast(f16x8, u1);
    f16x8 h2 = __builtin_bit_cast(f16x8, u2), h3 = __builtin_bit_cast(f16x8, u3);
    f16x8 h4 = __builtin_bit_cast(f16x8, u4), h5 = __builtin_bit_cast(f16x8, u5);
    f16x8 h6 = __builtin_bit_cast(f16x8, u6), h7 = __builtin_bit_cast(f16x8, u7);
#pragma unroll
    for (int j = 0; j < 8; j++)
      a[j] += ((float)h0[j] + (float)h1[j]) + ((float)h2[j] + (float)h3[j]) +
              ((float)h4[j] + (float)h5[j]) + ((float)h6[j] + (float)h7[j]);
  }
  for (; p + 2 <= p1; p += 2) {
    int s0 = csr_src[p], s1 = csr_src[p + 1];
    uint4 u0 = *(const uint4*)(h16 + (size_t)s0 * D + sub * 8);
    uint4 u1 = *(const uint4*)(h16 + (size_t)s1 * D + sub * 8);
    f16x8 h0 = __builtin_bit_cast(f16x8, u0), h1 = __builtin_bit_cast(f16x8, u1);
#pragma unroll
    for (int j = 0; j < 8; j++) a[j] += (float)h0[j] + (float)h1[j];
  }
  if (p < p1) {
    int s = csr_src[p];
    uint4 u = *(const uint4*)(h16 + (size_t)s * D + sub * 8);
    f16x8 h = __builtin_bit_cast(f16x8, u);
#pragma unroll
    for (int j = 0; j < 8; j++) a[j] += (float)h[j];
  }
  float scl = inv_deg[node];
  f16x8 o;
#pragma unroll
  for (int j = 0; j < 8; j++) o[j] = (_Float16)(a[j] * scl);
  *(uint4*)(out16 + (size_t)node * D + sub * 8) = __builtin_bit_cast(uint4, o);
}

// ---------------- MFMA GEMM with register-prefetch pipeline ----------------
// 128x128 block tile (NCOLS cols), 4 waves 2x2, K merged over NSRC*128, chunk 32.
// Per chunk: barrier; regs->LDS; barrier; issue next chunk's global loads; compute.
// LDS rows: 8 u64 data + 1 pad -> 72B stride (conflict-light b64 frag reads).

template <int NCOLS, int NSRC, bool RELU, bool OUTF16>
__global__ __launch_bounds__(256) void k_gemm(
    const unsigned short* __restrict__ in0, const unsigned short* __restrict__ in1,
    const unsigned short* __restrict__ wt, const float* __restrict__ bias,
    void* __restrict__ outp) {
  constexpr int CT = NCOLS / 32;
  constexpr int NCH = NSRC * 4;
  constexpr int WIT = (NCOLS * 4) / 256;  // 2 for NCOLS=128, 1 for 64
  __shared__ u64 sI[128][9];
  __shared__ u64 sW[NCOLS][9];

  const int tid = threadIdx.x;
  const int row0 = blockIdx.x * 128;
  const int lane = tid & 63;
  const int w = tid >> 6;
  const int wr = w >> 1, wc = w & 1;
  const int lrow = lane & 15, kb = lane >> 4;
  const int sr = tid >> 2, sq = tid & 3;

  f32x4 acc[4][CT];
#pragma unroll
  for (int i = 0; i < 4; i++)
#pragma unroll
    for (int j = 0; j < CT; j++) acc[i][j] = (f32x4){0.f, 0.f, 0.f, 0.f};

  u64 rA[2][2], rW[WIT][2];

  auto loadA = [&](int ch) {
    const unsigned short* inP = (NSRC == 2 && ch >= 4) ? in1 : in0;
    const int kc = (ch & 3) * 32;
#pragma unroll
    for (int it = 0; it < 2; ++it) {
      int g = row0 + sr + it * 64;
      u64 a = 0, b = 0;
      if (g < N_NODES) {
        const u64* pp = (const u64*)(inP + (size_t)g * D + kc + sq * 8);
        a = pp[0]; b = pp[1];
      }
      rA[it][0] = a; rA[it][1] = b;
    }
  };
  auto loadW = [&](int ch) {
    const int s = (NSRC == 2) ? (ch >> 2) : 0;
    const int kc = (ch & 3) * 32;
    const unsigned short* wP = wt + (size_t)s * NCOLS * D;
#pragma unroll
    for (int it = 0; it < WIT; ++it) {
      int c = sr + it * 64;
      const u64* pp = (const u64*)(wP + (size_t)c * D + kc + sq * 8);
      rW[it][0] = pp[0]; rW[it][1] = pp[1];
    }
  };

  loadA(0); loadW(0);
#pragma unroll
  for (int ch = 0; ch < NCH; ++ch) {
    __syncthreads();
#pragma unroll
    for (int it = 0; it < 2; ++it) {
      int r = sr + it * 64;
      sI[r][sq * 2] = rA[it][0]; sI[r][sq * 2 + 1] = rA[it][1];
    }
#pragma unroll
    for (int it = 0; it < WIT; ++it) {
      int c = sr + it * 64;
      sW[c][sq * 2] = rW[it][0]; sW[c][sq * 2 + 1] = rW[it][1];
    }
    __syncthreads();
    if (ch + 1 < NCH) { loadA(ch + 1); loadW(ch + 1); }

    f16x8 fA[4], fB[CT];
#pragma unroll
    for (int rt = 0; rt < 4; ++rt) {
      int rr = wr * 64 + rt * 16 + lrow;
      fA[rt] = mk16(sI[rr][kb * 2], sI[rr][kb * 2 + 1]);
    }
#pragma unroll
    for (int ct = 0; ct < CT; ++ct) {
      int cc = wc * (NCOLS / 2) + ct * 16 + lrow;
      fB[ct] = mk16(sW[cc][kb * 2], sW[cc][kb * 2 + 1]);
    }
#pragma unroll
    for (int ct = 0; ct < CT; ++ct)
#pragma unroll
      for (int rt = 0; rt < 4; ++rt)
        acc[rt][ct] = __builtin_amdgcn_mfma_f32_16x16x32_f16(fA[rt], fB[ct], acc[rt][ct], 0, 0, 0);
  }

#pragma unroll
  for (int ct = 0; ct < CT; ++ct) {
    int col = wc * (NCOLS / 2) + ct * 16 + lrow;
    float bv = bias[col];
#pragma unroll
    for (int rt = 0; rt < 4; ++rt) {
#pragma unroll
      for (int r = 0; r < 4; ++r) {
        int g = row0 + wr * 64 + rt * 16 + kb * 4 + r;
        if (g < N_NODES) {
          float v = acc[rt][ct][r] + bv;
          if (RELU) v = fmaxf(v, 0.f);
          if constexpr (OUTF16) {
            _Float16 hv = (_Float16)v;
            ((unsigned short*)outp)[(size_t)g * NCOLS + col] =
                __builtin_bit_cast(unsigned short, hv);
          } else {
            ((float*)outp)[(size_t)g * NCOLS + col] = v;
          }
        }
      }
    }
  }
}

// ---------------- launch ----------------

extern "C" void kernel_launch(void* const* d_in, const int* in_sizes, int n_in,
                              void* d_out, int out_size, void* d_ws, size_t ws_size,
                              hipStream_t stream) {
  const float* x = (const float*)d_in[0];
  const int* edge = (const int*)d_in[1];
  const int* src = edge;
  const int* dst = edge + N_EDGES;
  const float* Wl0 = (const float*)d_in[2];
  const float* bl0 = (const float*)d_in[3];
  const float* Wr0 = (const float*)d_in[4];
  const float* Wl1 = (const float*)d_in[5];
  const float* bl1 = (const float*)d_in[6];
  const float* Wr1 = (const float*)d_in[7];
  const float* Wl2 = (const float*)d_in[8];
  const float* bl2 = (const float*)d_in[9];
  const float* Wr2 = (const float*)d_in[10];
  const float* W = (const float*)d_in[11];
  const float* b = (const float*)d_in[12];
  float* out = (float*)d_out;
  (void)ws_size; (void)n_in; (void)in_sizes; (void)out_size;

  char* ws = (char*)d_ws;
  int* bucket_cur = (int*)(ws);                                  // NB ints
  int* row_start = (int*)(ws + (1ll << 20));                     // 400 KB
  int* row_end = (int*)(ws + (2ll << 20));                       // 400 KB
  float* inv_deg = (float*)(ws + (3ll << 20));                   // 400 KB
  int* csr_src = (int*)(ws + (4ll << 20));                       // 9.62 MB
  u32* binned = (u32*)(ws + (14ll << 20));                       // 9.62 MB
  unsigned short* wt16 = (unsigned short*)(ws + (24ll << 20));   // 208 KB
  unsigned short* x16 = (unsigned short*)(ws + (25ll << 20));    // 25.6 MB
  unsigned short* agg16 = (unsigned short*)(ws + (51ll << 20));  // 25.6 MB
  unsigned short* h16 = (unsigned short*)(ws + (77ll << 20));    // 25.6 MB -> ends ~103 MB

  k_convert_w<<<(6 * 16384 + 8192 + 255) / 256, 256, 0, stream>>>(
      Wl0, Wr0, Wl1, Wr1, Wl2, Wr2, W, wt16, bucket_cur);
  k_scatter<<<NBLK, 256, 0, stream>>>(src, dst, bucket_cur, binned);
  k_build<<<NB, 256, 0, stream>>>(binned, bucket_cur, row_start, row_end, inv_deg, csr_src);
  k_convert_x<<<6250, 256, 0, stream>>>(x, x16);

  const int agg_grid = (N_NODES + 15) / 16;
  const int gemm_grid = (N_NODES + 127) / 128;

  // layer 0
  k_agg<<<agg_grid, 256, 0, stream>>>(x16, row_start, row_end, inv_deg, csr_src, agg16);
  k_gemm<128, 2, true, true><<<gemm_grid, 256, 0, stream>>>(agg16, x16, wt16 + 0, bl0, h16);
  // layer 1
  k_agg<<<agg_grid, 256, 0, stream>>>(h16, row_start, row_end, inv_deg, csr_src, agg16);
  k_gemm<128, 2, true, true><<<gemm_grid, 256, 0, stream>>>(agg16, h16, wt16 + 32768, bl1, h16);
  // layer 2
  k_agg<<<agg_grid, 256, 0, stream>>>(h16, row_start, row_end, inv_deg, csr_src, agg16);
  k_gemm<128, 2, true, true><<<gemm_grid, 256, 0, stream>>>(agg16, h16, wt16 + 65536, bl2, h16);
  // final projection (f32 out)
  k_gemm<64, 1, false, false><<<gemm_grid, 256, 0, stream>>>(h16, nullptr, wt16 + 98304, b, out);
}